// Round 5
// baseline (565.754 us; speedup 1.0000x reference)
//
#include <hip/hip_runtime.h>

typedef float f32x4 __attribute__((ext_vector_type(4)));
typedef short bf16x8 __attribute__((ext_vector_type(8)));
typedef unsigned short u16;

#define NEG_INF (-1e30f)

__device__ __forceinline__ u16 f2bf(float f) {
    unsigned u = __builtin_bit_cast(unsigned, f);
    unsigned r = u + 0x7FFFu + ((u >> 16) & 1u);  // RNE
    return (u16)(r >> 16);
}
// 2x f32 -> packed bf16 in one VALU op (RNE, identical to f2bf; validated round 2).
__device__ __forceinline__ unsigned pk2(float a, float b) {
    unsigned r;
    asm("v_cvt_pk_bf16_f32 %0, %1, %2" : "=v"(r) : "v"(a), "v"(b));
    return r;
}

__device__ __forceinline__ float wave_max(float v) {
    #pragma unroll
    for (int o = 32; o > 0; o >>= 1) v = fmaxf(v, __shfl_xor(v, o, 64));
    return v;
}
__device__ __forceinline__ float wave_sum(float v) {
    #pragma unroll
    for (int o = 32; o > 0; o >>= 1) v += __shfl_xor(v, o, 64);
    return v;
}
__device__ __forceinline__ void wave_argmax(float& v, int& i) {
    #pragma unroll
    for (int o = 32; o > 0; o >>= 1) {
        float ov = __shfl_xor(v, o, 64);
        int oi = __shfl_xor(i, o, 64);
        if (ov > v || (ov == v && oi < i)) { v = ov; i = oi; }
    }
}

// ---------------- staging / swizzle ----------------
// Async global->LDS 16B. LDS dest is wave-uniform base + lane*16 in all uses below.
__device__ __forceinline__ void g2l16(const void* g, void* l) {
    __builtin_amdgcn_global_load_lds((__attribute__((address_space(1))) void*)g,
                                     (__attribute__((address_space(3))) void*)l,
                                     16, 0, 0);
}
// Bank-conflict swizzles on 16B chunk index (rule #21: LDS linear; swizzle applied to
// global SOURCE for g2l16 paths, to ds_write addr for reg-staged paths, and to all reads).
// Proven round 4: SQ_LDS_BANK_CONFLICT == 0.
__device__ __forceinline__ int swz8(int row, int c) { return c ^ (row & 7); }         // [*][64] tiles
__device__ __forceinline__ int swz4(int row, int c) { return c ^ ((row >> 1) & 3); }  // [*][32] tiles

// [ROWS][64] bf16 tile staged via global_load_lds, source pre-swizzled. 2 rounds.
template<int NTHR>
__device__ __forceinline__ void stageA64(const u16* __restrict__ src, int ld,
                                         u16* dst, int tid) {
    #pragma unroll
    for (int r = 0; r < 2; ++r) {
        int e = r * NTHR * 8 + tid * 8;
        int row = e >> 6, c = (e >> 3) & 7;
        g2l16(src + (size_t)row * ld + swz8(row, c) * 8, dst + e);
    }
}
// [128][32] bf16 tile (256 thr), source pre-swizzled. 2 rounds.
__device__ __forceinline__ void stageA32(const u16* __restrict__ src, int ld,
                                         u16* dst, int tid) {
    #pragma unroll
    for (int r = 0; r < 2; ++r) {
        int e = r * 2048 + tid * 8;
        int row = e >> 5, c = (e >> 3) & 3;
        g2l16(src + (size_t)row * ld + swz4(row, c) * 8, dst + e);
    }
}

// fp32 tile load->regs / cvt+write->LDS (issue-early / write-late split, T14).
// [64][64], 256 thr: 16 floats/thread.
__device__ __forceinline__ void loadT64_256(const float* __restrict__ src, int ld,
                                            int tid, float4* v) {
    int row = tid >> 2, col = (tid & 3) * 16;
    const float* s = src + (size_t)row * ld + col;
    v[0] = *reinterpret_cast<const float4*>(s);
    v[1] = *reinterpret_cast<const float4*>(s + 4);
    v[2] = *reinterpret_cast<const float4*>(s + 8);
    v[3] = *reinterpret_cast<const float4*>(s + 12);
}
__device__ __forceinline__ void writeT64_256(const float4* v, u16* dst, int tid) {
    int row = tid >> 2, c0 = (tid & 3) * 2;
    uint4 p0 = { pk2(v[0].x, v[0].y), pk2(v[0].z, v[0].w), pk2(v[1].x, v[1].y), pk2(v[1].z, v[1].w) };
    uint4 p1 = { pk2(v[2].x, v[2].y), pk2(v[2].z, v[2].w), pk2(v[3].x, v[3].y), pk2(v[3].z, v[3].w) };
    *reinterpret_cast<uint4*>(dst + row * 64 + swz8(row, c0) * 8) = p0;
    *reinterpret_cast<uint4*>(dst + row * 64 + swz8(row, c0 + 1) * 8) = p1;
}
// [128][32], 256 thr: 16 floats/thread.
__device__ __forceinline__ void loadT32(const float* __restrict__ src, int ld,
                                        int tid, float4* v) {
    int row = tid >> 1, col = (tid & 1) * 16;
    const float* s = src + (size_t)row * ld + col;
    v[0] = *reinterpret_cast<const float4*>(s);
    v[1] = *reinterpret_cast<const float4*>(s + 4);
    v[2] = *reinterpret_cast<const float4*>(s + 8);
    v[3] = *reinterpret_cast<const float4*>(s + 12);
}
__device__ __forceinline__ void writeT32(const float4* v, u16* dst, int tid) {
    int row = tid >> 1, c0 = (tid & 1) * 2;
    uint4 p0 = { pk2(v[0].x, v[0].y), pk2(v[0].z, v[0].w), pk2(v[1].x, v[1].y), pk2(v[1].z, v[1].w) };
    uint4 p1 = { pk2(v[2].x, v[2].y), pk2(v[2].z, v[2].w), pk2(v[3].x, v[3].y), pk2(v[3].z, v[3].w) };
    *reinterpret_cast<uint4*>(dst + row * 32 + swz4(row, c0) * 8) = p0;
    *reinterpret_cast<uint4*>(dst + row * 32 + swz4(row, c0 + 1) * 8) = p1;
}

// Swizzled frag reads. mfma_f32_16x16x32_bf16: lane holds [m|n=lane&15][k=ks*32+(lane>>4)*8..+7]
__device__ __forceinline__ bf16x8 frag64s(const u16* lds, int row0, int ks, int lane) {
    int row = row0 + (lane & 15);
    int c = ks * 4 + (lane >> 4);
    return *reinterpret_cast<const bf16x8*>(lds + row * 64 + swz8(row, c) * 8);
}
__device__ __forceinline__ bf16x8 frag32s(const u16* lds, int row0, int lane) {
    int row = row0 + (lane & 15);
    int c = lane >> 4;
    return *reinterpret_cast<const bf16x8*>(lds + row * 32 + swz4(row, c) * 8);
}

// ---------------- fp32 -> bf16 one-time conversions ----------------
// x [4096,1024] only (tier 1).
__global__ void conv_x(const float* __restrict__ s, u16* __restrict__ d) {
    size_t i = (size_t)blockIdx.x * 256 + threadIdx.x;   // float4 index
    float4 v = *reinterpret_cast<const float4*>(s + i * 4);
    uint2 pk;
    pk.x = pk2(v.x, v.y); pk.y = pk2(v.z, v.w);
    *reinterpret_cast<uint2*>(d + i * 4) = pk;
}
// All four 16MB arrays (x, gw, uw, dw), each exactly 1M float4 (tier 2).
__global__ void conv_all(const float* __restrict__ s0, const float* __restrict__ s1,
                         const float* __restrict__ s2, const float* __restrict__ s3,
                         u16* __restrict__ d0, u16* __restrict__ d1,
                         u16* __restrict__ d2, u16* __restrict__ d3) {
    int b = blockIdx.x, t = threadIdx.x;
    int seg = b >> 10;
    const float* s = seg == 0 ? s0 : seg == 1 ? s1 : seg == 2 ? s2 : s3;
    u16* d = seg == 0 ? d0 : seg == 1 ? d1 : seg == 2 ? d2 : d3;
    int base = (b & 1023) * 256 + t;
    #pragma unroll
    for (int j = 0; j < 4; ++j) {
        size_t i = (size_t)base + (size_t)j * 262144;
        float4 v = *reinterpret_cast<const float4*>(s + i * 4);
        uint2 pk;
        pk.x = pk2(v.x, v.y); pk.y = pk2(v.z, v.w);
        *reinterpret_cast<uint2*>(d + i * 4) = pk;
    }
}

// ---------------- router GEMM: R[4096,256] = x @ [rxw;ryw]^T ----------------
// 64x64 tile, BK=64, 4 waves (2x2 of 32x32), dbuf 2-phase, grid (4,64)=256 blocks.
template<bool ABF>
__global__ __launch_bounds__(256, 2) void gemm_router(
    const float* __restrict__ Xf, const u16* __restrict__ Xb,
    const float* __restrict__ RX, const float* __restrict__ RY,
    float* __restrict__ R) {
    __shared__ __align__(16) u16 As[2][4096];
    __shared__ __align__(16) u16 Bs[2][4096];
    int tid = threadIdx.x, lane = tid & 63, wave = tid >> 6;
    int rowBase = blockIdx.y * 64, colBase = blockIdx.x * 64;
    const float* Bp = (blockIdx.x < 2) ? RX + (size_t)colBase * 1024
                                       : RY + (size_t)(colBase - 128) * 1024;
    int wm = (wave >> 1) * 32, wn = (wave & 1) * 32;
    f32x4 acc[2][2] = {};
    float4 av[4], bv[4];
    if constexpr (ABF) stageA64<256>(Xb + (size_t)rowBase * 1024, 1024, As[0], tid);
    else               { loadT64_256(Xf + (size_t)rowBase * 1024, 1024, tid, av);
                         writeT64_256(av, As[0], tid); }
    loadT64_256(Bp, 1024, tid, bv);
    writeT64_256(bv, Bs[0], tid);
    __syncthreads();
    int cur = 0;
    for (int t = 0; t < 16; ++t) {
        if (t < 15) {  // issue next tile BEFORE compute (latency hides under MFMA)
            int k0 = (t + 1) * 64;
            if constexpr (ABF) stageA64<256>(Xb + (size_t)rowBase * 1024 + k0, 1024, As[cur ^ 1], tid);
            else               loadT64_256(Xf + (size_t)rowBase * 1024 + k0, 1024, tid, av);
            loadT64_256(Bp + k0, 1024, tid, bv);
        }
        #pragma unroll
        for (int ks = 0; ks < 2; ++ks) {
            bf16x8 af[2], bfr[2];
            #pragma unroll
            for (int i = 0; i < 2; ++i) af[i] = frag64s(As[cur], wm + i * 16, ks, lane);
            #pragma unroll
            for (int j = 0; j < 2; ++j) bfr[j] = frag64s(Bs[cur], wn + j * 16, ks, lane);
            #pragma unroll
            for (int i = 0; i < 2; ++i)
                #pragma unroll
                for (int j = 0; j < 2; ++j)
                    acc[i][j] = __builtin_amdgcn_mfma_f32_16x16x32_bf16(af[i], bfr[j], acc[i][j], 0, 0, 0);
        }
        if (t < 15) {
            if constexpr (!ABF) writeT64_256(av, As[cur ^ 1], tid);
            writeT64_256(bv, Bs[cur ^ 1], tid);
        }
        __syncthreads();   // single barrier/iter: drains next-tile stores + orders buffers
        cur ^= 1;
    }
    int rq = (lane >> 4) * 4, cq = lane & 15;
    #pragma unroll
    for (int i = 0; i < 2; ++i)
        #pragma unroll
        for (int j = 0; j < 2; ++j) {
            int col = colBase + wn + j * 16 + cq;
            #pragma unroll
            for (int r = 0; r < 4; ++r) {
                int row = rowBase + wm + i * 16 + rq + r;
                R[(size_t)row * 256 + col] = acc[i][j][r];
            }
        }
}

// ---------------- gateup: 128x128 tile, BK=32, dbuf 2-phase, 4 waves 2x2 of 64x64 -------
// H2 = silu(x Gt) * (x Ut), bf16. Grid 1024, XCD decode.
// MODE: 0 = all fp32 reg-staged; 1 = xb g2l16, W fp32 reg-staged; 2 = all bf16 g2l16.
template<int MODE>
__global__ __launch_bounds__(256, 3) void gemm_gateup(
    const float* __restrict__ Xf, const u16* __restrict__ Xb,
    const float* __restrict__ GWf, const float* __restrict__ UWf,
    const u16* __restrict__ GWb, const u16* __restrict__ UWb,
    u16* __restrict__ H2) {
    __shared__ __align__(16) u16 As[2][4096];
    __shared__ __align__(16) u16 Gs[2][4096];
    __shared__ __align__(16) u16 Us[2][4096];
    int tid = threadIdx.x, lane = tid & 63, wave = tid >> 6;
    int b = blockIdx.x, xcd = b & 7, ii = b >> 3;
    int by = xcd * 4 + (ii >> 5), bx = ii & 31;
    int rowBase = by * 128, colBase = bx * 128;
    int wm = (wave >> 1) * 64, wn = (wave & 1) * 64;
    f32x4 accg[4][4] = {}, accu[4][4] = {};
    float4 av[4], gv[4], uv[4];
    if constexpr (MODE >= 1) stageA32(Xb + (size_t)rowBase * 1024, 1024, As[0], tid);
    else                     { loadT32(Xf + (size_t)rowBase * 1024, 1024, tid, av);
                               writeT32(av, As[0], tid); }
    if constexpr (MODE == 2) {
        stageA32(GWb + (size_t)colBase * 1024, 1024, Gs[0], tid);
        stageA32(UWb + (size_t)colBase * 1024, 1024, Us[0], tid);
    } else {
        loadT32(GWf + (size_t)colBase * 1024, 1024, tid, gv);
        loadT32(UWf + (size_t)colBase * 1024, 1024, tid, uv);
        writeT32(gv, Gs[0], tid);
        writeT32(uv, Us[0], tid);
    }
    __syncthreads();
    int cur = 0;
    for (int t = 0; t < 32; ++t) {
        if (t < 31) {
            int k0 = (t + 1) * 32;
            if constexpr (MODE >= 1) stageA32(Xb + (size_t)rowBase * 1024 + k0, 1024, As[cur ^ 1], tid);
            else                     loadT32(Xf + (size_t)rowBase * 1024 + k0, 1024, tid, av);
            if constexpr (MODE == 2) {
                stageA32(GWb + (size_t)colBase * 1024 + k0, 1024, Gs[cur ^ 1], tid);
                stageA32(UWb + (size_t)colBase * 1024 + k0, 1024, Us[cur ^ 1], tid);
            } else {
                loadT32(GWf + (size_t)colBase * 1024 + k0, 1024, tid, gv);
                loadT32(UWf + (size_t)colBase * 1024 + k0, 1024, tid, uv);
            }
        }
        bf16x8 gf[4], uf[4];
        #pragma unroll
        for (int j = 0; j < 4; ++j) { gf[j] = frag32s(Gs[cur], wn + j * 16, lane);
                                      uf[j] = frag32s(Us[cur], wn + j * 16, lane); }
        #pragma unroll
        for (int i = 0; i < 4; ++i) {
            bf16x8 af = frag32s(As[cur], wm + i * 16, lane);
            #pragma unroll
            for (int j = 0; j < 4; ++j) {
                accg[i][j] = __builtin_amdgcn_mfma_f32_16x16x32_bf16(af, gf[j], accg[i][j], 0, 0, 0);
                accu[i][j] = __builtin_amdgcn_mfma_f32_16x16x32_bf16(af, uf[j], accu[i][j], 0, 0, 0);
            }
        }
        if (t < 31) {
            if constexpr (MODE == 0) writeT32(av, As[cur ^ 1], tid);
            if constexpr (MODE < 2) { writeT32(gv, Gs[cur ^ 1], tid);
                                      writeT32(uv, Us[cur ^ 1], tid); }
        }
        __syncthreads();
        cur ^= 1;
    }
    int rq = (lane >> 4) * 4, cq = lane & 15;
    #pragma unroll
    for (int i = 0; i < 4; ++i)
        #pragma unroll
        for (int j = 0; j < 4; ++j) {
            int col = colBase + wn + j * 16 + cq;
            #pragma unroll
            for (int r = 0; r < 4; ++r) {
                int row = rowBase + wm + i * 16 + rq + r;
                float gvv = accg[i][j][r], uvv = accu[i][j][r];
                float h = (gvv / (1.f + __expf(-gvv))) * uvv;   // silu(g)*u
                H2[(size_t)row * 4096 + col] = f2bf(h);
            }
        }
}

// ---------------- down: Out += H2 @ dw^T. 64x64 tile, BK=64, 256 thr (4 waves 2x2 of
// 32x32), dbuf 2-phase, grid 1024 (4 blk/CU), XCD decode (8 row-panels/XCD = 4MB L2). ----
template<bool BW16>
__global__ __launch_bounds__(256, 4) void gemm_down64(
    const u16* __restrict__ H2, const float* __restrict__ DWf, const u16* __restrict__ DWb,
    float* __restrict__ Out) {
    __shared__ __align__(16) u16 As[2][4096];
    __shared__ __align__(16) u16 Bs[2][4096];
    int tid = threadIdx.x, lane = tid & 63, wave = tid >> 6;
    int b = blockIdx.x, xcd = b & 7, ii = b >> 3;
    int by = xcd * 8 + (ii >> 4), bx = ii & 15;
    int rowBase = by * 64, colBase = bx * 64;
    const u16* Ap = H2 + (size_t)rowBase * 4096;
    int wm = (wave >> 1) * 32, wn = (wave & 1) * 32;
    f32x4 acc[2][2] = {};
    float4 bv[4];
    stageA64<256>(Ap, 4096, As[0], tid);
    if constexpr (BW16) stageA64<256>(DWb + (size_t)colBase * 4096, 4096, Bs[0], tid);
    else                { loadT64_256(DWf + (size_t)colBase * 4096, 4096, tid, bv);
                          writeT64_256(bv, Bs[0], tid); }
    __syncthreads();
    int cur = 0;
    for (int t = 0; t < 64; ++t) {
        if (t < 63) {
            int k0 = (t + 1) * 64;
            stageA64<256>(Ap + k0, 4096, As[cur ^ 1], tid);
            if constexpr (BW16) stageA64<256>(DWb + (size_t)colBase * 4096 + k0, 4096, Bs[cur ^ 1], tid);
            else                loadT64_256(DWf + (size_t)colBase * 4096 + k0, 4096, tid, bv);
        }
        #pragma unroll
        for (int ks = 0; ks < 2; ++ks) {
            bf16x8 af[2], bfr[2];
            #pragma unroll
            for (int i = 0; i < 2; ++i) af[i] = frag64s(As[cur], wm + i * 16, ks, lane);
            #pragma unroll
            for (int j = 0; j < 2; ++j) bfr[j] = frag64s(Bs[cur], wn + j * 16, ks, lane);
            #pragma unroll
            for (int i = 0; i < 2; ++i)
                #pragma unroll
                for (int j = 0; j < 2; ++j)
                    acc[i][j] = __builtin_amdgcn_mfma_f32_16x16x32_bf16(af[i], bfr[j], acc[i][j], 0, 0, 0);
        }
        if (t < 63) { if constexpr (!BW16) writeT64_256(bv, Bs[cur ^ 1], tid); }
        __syncthreads();
        cur ^= 1;
    }
    int rq = (lane >> 4) * 4, cq = lane & 15;
    #pragma unroll
    for (int i = 0; i < 2; ++i)
        #pragma unroll
        for (int j = 0; j < 2; ++j) {
            int col = colBase + wn + j * 16 + cq;
            #pragma unroll
            for (int r = 0; r < 4; ++r) {
                int row = rowBase + wm + i * 16 + rq + r;
                size_t o = (size_t)row * 1024 + col;
                Out[o] = acc[i][j][r] + Out[o];   // add experts term (same-thread RMW)
            }
        }
}

// ---------------- expert combine (round-1 exact: 4.6KB LDS, high occupancy) -------------
__global__ __launch_bounds__(256) void expert_store(
    const float* __restrict__ X, const float* __restrict__ UE, const float* __restrict__ DE,
    const int* __restrict__ idxs, const float* __restrict__ wts, float* __restrict__ Out) {
    int n = blockIdx.x, tid = threadIdx.x;
    int lane = tid & 63, wave = tid >> 6;
    __shared__ float xs[1024];
    __shared__ float ews[16];
    __shared__ int sidx[16];
    __shared__ float swt[16];
    if (tid < 16) {
        sidx[tid] = min(max(idxs[n * 16 + tid], 0), 16383);  // clamp: no wild gathers
        swt[tid] = wts[n * 16 + tid];
    }
    {
        float4 v = reinterpret_cast<const float4*>(X + (size_t)n * 1024)[tid];
        *reinterpret_cast<float4*>(xs + tid * 4) = v;
    }
    __syncthreads();
    #pragma unroll
    for (int q = 0; q < 4; ++q) {
        int e = wave * 4 + q;
        const float* row = UE + (size_t)sidx[e] * 1024;
        float acc = 0.f;
        #pragma unroll
        for (int c = 0; c < 4; ++c) {
            int h = c * 256 + lane * 4;
            float4 a = *reinterpret_cast<const float4*>(row + h);
            float4 xv = *reinterpret_cast<const float4*>(xs + h);
            acc += a.x * xv.x + a.y * xv.y + a.z * xv.z + a.w * xv.w;
        }
        acc = wave_sum(acc);
        if (lane == 0) {
            float s = acc / (1.f + __expf(-acc));   // silu
            ews[e] = s * swt[e];
        }
    }
    __syncthreads();
    float4 a = make_float4(0.f, 0.f, 0.f, 0.f);
    int h = tid * 4;
    #pragma unroll
    for (int e = 0; e < 16; ++e) {
        const float* row = DE + (size_t)sidx[e] * 1024;
        float4 v = *reinterpret_cast<const float4*>(row + h);
        float w = ews[e];
        a.x += w * v.x; a.y += w * v.y;
        a.z += w * v.z; a.w += w * v.w;
    }
    reinterpret_cast<float4*>(Out + (size_t)n * 1024)[tid] = a;
}

// ---------------- router stats / topk (proven) ----------------
__global__ void bn_stats(const float* __restrict__ R, float* __restrict__ stats) {
    int c = threadIdx.x;
    int r0 = blockIdx.x * 64;
    float s = 0.f, s2 = 0.f;
    for (int r = r0; r < r0 + 64; ++r) {
        float v = R[(size_t)r * 256 + c];
        s += v; s2 += v * v;
    }
    atomicAdd(&stats[c], s);
    atomicAdd(&stats[256 + c], s2);
}

__global__ __launch_bounds__(64) void router_topk(
    const float* __restrict__ R, const float* __restrict__ stats,
    int* __restrict__ idx_out, float* __restrict__ wt_out) {
    int n = blockIdx.x, lane = threadIdx.x;
    const float invN = 1.0f / 4096.0f;
    float z[4];
    #pragma unroll
    for (int p = 0; p < 4; ++p) {
        int c = p * 64 + lane;
        float mean = stats[c] * invN;
        float var = fmaxf(stats[256 + c] * invN - mean * mean, 0.f);  // biased var
        float v = R[(size_t)n * 256 + c];
        z[p] = (v - mean) * rsqrtf(var + 1e-5f);
    }
    float mx = wave_max(fmaxf(z[0], z[1]));
    float sx = __logf(wave_sum(__expf(z[0] - mx) + __expf(z[1] - mx)));
    float lx0 = z[0] - mx - sx, lx1 = z[1] - mx - sx;
    float my = wave_max(fmaxf(z[2], z[3]));
    float sy = __logf(wave_sum(__expf(z[2] - my) + __expf(z[3] - my)));
    float ly0 = z[2] - my - sy, ly1 = z[3] - my - sy;

    __shared__ float tx[16], ty[16];
    __shared__ int txc[16], tyc[16];
    float v0 = lx0, v1 = lx1;
    for (int t = 0; t < 16; ++t) {
        float bv; int bc;
        if (v1 > v0) { bv = v1; bc = lane + 64; } else { bv = v0; bc = lane; }
        wave_argmax(bv, bc);
        if (lane == 0) { tx[t] = bv; txc[t] = bc; }
        if (bc == lane) v0 = NEG_INF;
        else if (bc == lane + 64) v1 = NEG_INF;
    }
    v0 = ly0; v1 = ly1;
    for (int t = 0; t < 16; ++t) {
        float bv; int bc;
        if (v1 > v0) { bv = v1; bc = lane + 64; } else { bv = v0; bc = lane; }
        wave_argmax(bv, bc);
        if (lane == 0) { ty[t] = bv; tyc[t] = bc; }
        if (bc == lane) v0 = NEG_INF;
        else if (bc == lane + 64) v1 = NEG_INF;
    }
    __syncthreads();
    float cv[4]; int ci[4];
    #pragma unroll
    for (int p = 0; p < 4; ++p) {
        int pid = p * 64 + lane;
        cv[p] = tx[pid >> 4] + ty[pid & 15];
        ci[p] = pid;
    }
    for (int t = 0; t < 16; ++t) {
        float bv = cv[0]; int bc = ci[0];
        #pragma unroll
        for (int p = 1; p < 4; ++p)
            if (cv[p] > bv) { bv = cv[p]; bc = ci[p]; }
        wave_argmax(bv, bc);
        if (lane == 0) {
            idx_out[n * 16 + t] = txc[bc >> 4] * 128 + tyc[bc & 15];
            wt_out[n * 16 + t] = __expf(bv);
        }
        #pragma unroll
        for (int p = 0; p < 4; ++p)
            if (ci[p] == bc) cv[p] = NEG_INF;
    }
}

// ---------------- host ----------------
// Workspace tiers:
//   base 34.1MB: stats 16K | idx 256K | wt 256K | union32 { R 4MB -> H2 32MB }
//   tier1 (+xb 8MB, >=42,483,712): x pre-converted -> router/gateup A via g2l16
//   tier2 (+gwb,uwb,dwb 24MB, >=67,649,536): ALL GEMM operands bf16 -> pure g2l16 staging
// All conversions are the same RNE cast previously applied in-flight: bit-identical output.
extern "C" void kernel_launch(void* const* d_in, const int* in_sizes, int n_in,
                              void* d_out, int out_size, void* d_ws, size_t ws_size,
                              hipStream_t stream) {
    const float* x   = (const float*)d_in[0];   // [4096,1024]
    const float* gw  = (const float*)d_in[1];   // [4096,1024]
    const float* uw  = (const float*)d_in[2];   // [4096,1024]
    const float* dw  = (const float*)d_in[3];   // [1024,4096]
    const float* rxw = (const float*)d_in[4];   // [128,1024]
    const float* ryw = (const float*)d_in[5];   // [128,1024]
    const float* ue  = (const float*)d_in[6];   // [16384,1024]
    const float* de  = (const float*)d_in[7];   // [16384,1024]
    float* out = (float*)d_out;                 // [4096,1024] fp32

    char* p = (char*)d_ws;
    float* stats = (float*)p; p += 16384;
    int*   idxb  = (int*)p;   p += 262144;
    float* wtb   = (float*)p; p += 262144;
    float* R     = (float*)p;                   // [4096,256] fp32, dead after router_topk
    u16*   H2    = (u16*)p;                     // aliases R: [4096,4096] bf16 (dense phase)

    u16* xb  = (u16*)((char*)d_ws + 34095104ull);
    u16* gwb = (u16*)((char*)d_ws + 42483712ull);
    u16* uwb = (u16*)((char*)d_ws + 50872320ull);
    u16* dwb = (u16*)((char*)d_ws + 59260928ull);
    int tier = ws_size >= 67649536ull ? 2 : ws_size >= 42483712ull ? 1 : 0;

    hipMemsetAsync(stats, 0, 512 * sizeof(float), stream);
    if (tier == 2)      conv_all<<<4096, 256, 0, stream>>>(x, gw, uw, dw, xb, gwb, uwb, dwb);
    else if (tier == 1) conv_x<<<4096, 256, 0, stream>>>(x, xb);

    if (tier >= 1) gemm_router<true ><<<dim3(4, 64), 256, 0, stream>>>(x, xb, rxw, ryw, R);
    else           gemm_router<false><<<dim3(4, 64), 256, 0, stream>>>(x, (const u16*)x, rxw, ryw, R);
    bn_stats<<<64, 256, 0, stream>>>(R, stats);
    router_topk<<<4096, 64, 0, stream>>>(R, stats, idxb, wtb);
    expert_store<<<4096, 256, 0, stream>>>(x, ue, de, idxb, wtb, out);   // experts -> out

    if (tier == 2)      gemm_gateup<2><<<1024, 256, 0, stream>>>(x, xb, gw, uw, gwb, uwb, H2);
    else if (tier == 1) gemm_gateup<1><<<1024, 256, 0, stream>>>(x, xb, gw, uw, nullptr, nullptr, H2);
    else                gemm_gateup<0><<<1024, 256, 0, stream>>>(x, (const u16*)x, gw, uw, nullptr, nullptr, H2);

    if (tier == 2) gemm_down64<true ><<<1024, 256, 0, stream>>>(H2, dw, dwb, out);
    else           gemm_down64<false><<<1024, 256, 0, stream>>>(H2, dw, (const u16*)dw, out);
}

// Round 6
// 463.963 us; speedup vs baseline: 1.2194x; 1.2194x over previous
//
#include <hip/hip_runtime.h>

typedef float f32x4 __attribute__((ext_vector_type(4)));
typedef short bf16x8 __attribute__((ext_vector_type(8)));
typedef unsigned short u16;

#define NEG_INF (-1e30f)

__device__ __forceinline__ u16 f2bf(float f) {
    unsigned u = __builtin_bit_cast(unsigned, f);
    unsigned r = u + 0x7FFFu + ((u >> 16) & 1u);  // RNE
    return (u16)(r >> 16);
}
// 2x f32 -> packed bf16 in one VALU op (RNE, identical to f2bf; validated round 2).
__device__ __forceinline__ unsigned pk2(float a, float b) {
    unsigned r;
    asm("v_cvt_pk_bf16_f32 %0, %1, %2" : "=v"(r) : "v"(a), "v"(b));
    return r;
}

__device__ __forceinline__ float wave_max(float v) {
    #pragma unroll
    for (int o = 32; o > 0; o >>= 1) v = fmaxf(v, __shfl_xor(v, o, 64));
    return v;
}
__device__ __forceinline__ float wave_sum(float v) {
    #pragma unroll
    for (int o = 32; o > 0; o >>= 1) v += __shfl_xor(v, o, 64);
    return v;
}
__device__ __forceinline__ void wave_argmax(float& v, int& i) {
    #pragma unroll
    for (int o = 32; o > 0; o >>= 1) {
        float ov = __shfl_xor(v, o, 64);
        int oi = __shfl_xor(i, o, 64);
        if (ov > v || (ov == v && oi < i)) { v = ov; i = oi; }
    }
}

// ---------------- staging / swizzle ----------------
// Async global->LDS 16B. LDS dest is wave-uniform base + lane*16 in all uses below.
// NOTE (round-5 lesson): the LDS-DMA path is a single queue — use it for ONE operand
// per kernel and reg-stage the rest (mixed paths run in parallel; all-DMA serializes).
__device__ __forceinline__ void g2l16(const void* g, void* l) {
    __builtin_amdgcn_global_load_lds((__attribute__((address_space(1))) void*)g,
                                     (__attribute__((address_space(3))) void*)l,
                                     16, 0, 0);
}
// Bank-conflict swizzles on 16B chunk index (rule #21: LDS linear; swizzle applied to
// global SOURCE for g2l16 paths, to ds_write addr for reg-staged paths, and to all reads).
// Proven round 4: SQ_LDS_BANK_CONFLICT == 0.
__device__ __forceinline__ int swz8(int row, int c) { return c ^ (row & 7); }         // [*][64] tiles
__device__ __forceinline__ int swz4(int row, int c) { return c ^ ((row >> 1) & 3); }  // [*][32] tiles

// [ROWS][64] bf16 tile staged via global_load_lds, source pre-swizzled. 2 rounds.
template<int NTHR>
__device__ __forceinline__ void stageA64(const u16* __restrict__ src, int ld,
                                         u16* dst, int tid) {
    #pragma unroll
    for (int r = 0; r < 2; ++r) {
        int e = r * NTHR * 8 + tid * 8;
        int row = e >> 6, c = (e >> 3) & 7;
        g2l16(src + (size_t)row * ld + swz8(row, c) * 8, dst + e);
    }
}
// [128][32] bf16 tile (256 thr), source pre-swizzled. 2 rounds.
__device__ __forceinline__ void stageA32(const u16* __restrict__ src, int ld,
                                         u16* dst, int tid) {
    #pragma unroll
    for (int r = 0; r < 2; ++r) {
        int e = r * 2048 + tid * 8;
        int row = e >> 5, c = (e >> 3) & 3;
        g2l16(src + (size_t)row * ld + swz4(row, c) * 8, dst + e);
    }
}

// fp32 tile load->regs / cvt+write->LDS (issue-early / write-late split, T14).
// [64][64], 256 thr: 16 floats/thread.
__device__ __forceinline__ void loadT64_256(const float* __restrict__ src, int ld,
                                            int tid, float4* v) {
    int row = tid >> 2, col = (tid & 3) * 16;
    const float* s = src + (size_t)row * ld + col;
    v[0] = *reinterpret_cast<const float4*>(s);
    v[1] = *reinterpret_cast<const float4*>(s + 4);
    v[2] = *reinterpret_cast<const float4*>(s + 8);
    v[3] = *reinterpret_cast<const float4*>(s + 12);
}
__device__ __forceinline__ void writeT64_256(const float4* v, u16* dst, int tid) {
    int row = tid >> 2, c0 = (tid & 3) * 2;
    uint4 p0 = { pk2(v[0].x, v[0].y), pk2(v[0].z, v[0].w), pk2(v[1].x, v[1].y), pk2(v[1].z, v[1].w) };
    uint4 p1 = { pk2(v[2].x, v[2].y), pk2(v[2].z, v[2].w), pk2(v[3].x, v[3].y), pk2(v[3].z, v[3].w) };
    *reinterpret_cast<uint4*>(dst + row * 64 + swz8(row, c0) * 8) = p0;
    *reinterpret_cast<uint4*>(dst + row * 64 + swz8(row, c0 + 1) * 8) = p1;
}
// [128][32] fp32, 256 thr: 16 floats/thread.
__device__ __forceinline__ void loadT32(const float* __restrict__ src, int ld,
                                        int tid, float4* v) {
    int row = tid >> 1, col = (tid & 1) * 16;
    const float* s = src + (size_t)row * ld + col;
    v[0] = *reinterpret_cast<const float4*>(s);
    v[1] = *reinterpret_cast<const float4*>(s + 4);
    v[2] = *reinterpret_cast<const float4*>(s + 8);
    v[3] = *reinterpret_cast<const float4*>(s + 12);
}
__device__ __forceinline__ void writeT32(const float4* v, u16* dst, int tid) {
    int row = tid >> 1, c0 = (tid & 1) * 2;
    uint4 p0 = { pk2(v[0].x, v[0].y), pk2(v[0].z, v[0].w), pk2(v[1].x, v[1].y), pk2(v[1].z, v[1].w) };
    uint4 p1 = { pk2(v[2].x, v[2].y), pk2(v[2].z, v[2].w), pk2(v[3].x, v[3].y), pk2(v[3].z, v[3].w) };
    *reinterpret_cast<uint4*>(dst + row * 32 + swz4(row, c0) * 8) = p0;
    *reinterpret_cast<uint4*>(dst + row * 32 + swz4(row, c0 + 1) * 8) = p1;
}

// bf16 tile reg-staging (issue-early / write-late), 2x uint4 per thread.
// [128][32] (256 thr): thread t -> row t>>1, chunks (t&1)*2, (t&1)*2+1.
__device__ __forceinline__ void loadB32bf(const u16* __restrict__ src, int ld,
                                          int tid, uint4* v) {
    int row = tid >> 1, c0 = (tid & 1) * 2;
    const u16* s = src + (size_t)row * ld;
    v[0] = *reinterpret_cast<const uint4*>(s + c0 * 8);
    v[1] = *reinterpret_cast<const uint4*>(s + (c0 + 1) * 8);
}
__device__ __forceinline__ void writeB32bf(const uint4* v, u16* dst, int tid) {
    int row = tid >> 1, c0 = (tid & 1) * 2;
    *reinterpret_cast<uint4*>(dst + row * 32 + swz4(row, c0) * 8) = v[0];
    *reinterpret_cast<uint4*>(dst + row * 32 + swz4(row, c0 + 1) * 8) = v[1];
}
// [64][64] (256 thr): thread t -> row t>>2, chunks (t&3)*2, (t&3)*2+1.
__device__ __forceinline__ void loadB64bf(const u16* __restrict__ src, int ld,
                                          int tid, uint4* v) {
    int row = tid >> 2, c0 = (tid & 3) * 2;
    const u16* s = src + (size_t)row * ld;
    v[0] = *reinterpret_cast<const uint4*>(s + c0 * 8);
    v[1] = *reinterpret_cast<const uint4*>(s + (c0 + 1) * 8);
}
__device__ __forceinline__ void writeB64bf(const uint4* v, u16* dst, int tid) {
    int row = tid >> 2, c0 = (tid & 3) * 2;
    *reinterpret_cast<uint4*>(dst + row * 64 + swz8(row, c0) * 8) = v[0];
    *reinterpret_cast<uint4*>(dst + row * 64 + swz8(row, c0 + 1) * 8) = v[1];
}

// Swizzled frag reads. mfma_f32_16x16x32_bf16: lane holds [m|n=lane&15][k=ks*32+(lane>>4)*8..+7]
__device__ __forceinline__ bf16x8 frag64s(const u16* lds, int row0, int ks, int lane) {
    int row = row0 + (lane & 15);
    int c = ks * 4 + (lane >> 4);
    return *reinterpret_cast<const bf16x8*>(lds + row * 64 + swz8(row, c) * 8);
}
__device__ __forceinline__ bf16x8 frag32s(const u16* lds, int row0, int lane) {
    int row = row0 + (lane & 15);
    int c = lane >> 4;
    return *reinterpret_cast<const bf16x8*>(lds + row * 32 + swz4(row, c) * 8);
}

// ---------------- fp32 -> bf16 one-time conversions ----------------
__global__ void conv_x(const float* __restrict__ s, u16* __restrict__ d) {
    size_t i = (size_t)blockIdx.x * 256 + threadIdx.x;   // float4 index
    float4 v = *reinterpret_cast<const float4*>(s + i * 4);
    uint2 pk;
    pk.x = pk2(v.x, v.y); pk.y = pk2(v.z, v.w);
    *reinterpret_cast<uint2*>(d + i * 4) = pk;
}
// All four 16MB arrays (x, gw, uw, dw), each exactly 1M float4.
__global__ void conv_all(const float* __restrict__ s0, const float* __restrict__ s1,
                         const float* __restrict__ s2, const float* __restrict__ s3,
                         u16* __restrict__ d0, u16* __restrict__ d1,
                         u16* __restrict__ d2, u16* __restrict__ d3) {
    int b = blockIdx.x, t = threadIdx.x;
    int seg = b >> 10;
    const float* s = seg == 0 ? s0 : seg == 1 ? s1 : seg == 2 ? s2 : s3;
    u16* d = seg == 0 ? d0 : seg == 1 ? d1 : seg == 2 ? d2 : d3;
    int base = (b & 1023) * 256 + t;
    #pragma unroll
    for (int j = 0; j < 4; ++j) {
        size_t i = (size_t)base + (size_t)j * 262144;
        float4 v = *reinterpret_cast<const float4*>(s + i * 4);
        uint2 pk;
        pk.x = pk2(v.x, v.y); pk.y = pk2(v.z, v.w);
        *reinterpret_cast<uint2*>(d + i * 4) = pk;
    }
}

// ---------------- router GEMM: R[4096,256] = x @ [rxw;ryw]^T ----------------
// 64x64 tile, BK=64, 4 waves (2x2 of 32x32), dbuf 2-phase, grid (4,64)=256 blocks.
template<bool ABF>
__global__ __launch_bounds__(256, 2) void gemm_router(
    const float* __restrict__ Xf, const u16* __restrict__ Xb,
    const float* __restrict__ RX, const float* __restrict__ RY,
    float* __restrict__ R) {
    __shared__ __align__(16) u16 As[2][4096];
    __shared__ __align__(16) u16 Bs[2][4096];
    int tid = threadIdx.x, lane = tid & 63, wave = tid >> 6;
    int rowBase = blockIdx.y * 64, colBase = blockIdx.x * 64;
    const float* Bp = (blockIdx.x < 2) ? RX + (size_t)colBase * 1024
                                       : RY + (size_t)(colBase - 128) * 1024;
    int wm = (wave >> 1) * 32, wn = (wave & 1) * 32;
    f32x4 acc[2][2] = {};
    float4 av[4], bv[4];
    if constexpr (ABF) stageA64<256>(Xb + (size_t)rowBase * 1024, 1024, As[0], tid);
    else               { loadT64_256(Xf + (size_t)rowBase * 1024, 1024, tid, av);
                         writeT64_256(av, As[0], tid); }
    loadT64_256(Bp, 1024, tid, bv);
    writeT64_256(bv, Bs[0], tid);
    __syncthreads();
    int cur = 0;
    for (int t = 0; t < 16; ++t) {
        if (t < 15) {  // issue next tile BEFORE compute (latency hides under MFMA)
            int k0 = (t + 1) * 64;
            if constexpr (ABF) stageA64<256>(Xb + (size_t)rowBase * 1024 + k0, 1024, As[cur ^ 1], tid);
            else               loadT64_256(Xf + (size_t)rowBase * 1024 + k0, 1024, tid, av);
            loadT64_256(Bp + k0, 1024, tid, bv);
        }
        #pragma unroll
        for (int ks = 0; ks < 2; ++ks) {
            bf16x8 af[2], bfr[2];
            #pragma unroll
            for (int i = 0; i < 2; ++i) af[i] = frag64s(As[cur], wm + i * 16, ks, lane);
            #pragma unroll
            for (int j = 0; j < 2; ++j) bfr[j] = frag64s(Bs[cur], wn + j * 16, ks, lane);
            #pragma unroll
            for (int i = 0; i < 2; ++i)
                #pragma unroll
                for (int j = 0; j < 2; ++j)
                    acc[i][j] = __builtin_amdgcn_mfma_f32_16x16x32_bf16(af[i], bfr[j], acc[i][j], 0, 0, 0);
        }
        if (t < 15) {
            if constexpr (!ABF) writeT64_256(av, As[cur ^ 1], tid);
            writeT64_256(bv, Bs[cur ^ 1], tid);
        }
        __syncthreads();   // single barrier/iter: drains next-tile stores + orders buffers
        cur ^= 1;
    }
    int rq = (lane >> 4) * 4, cq = lane & 15;
    #pragma unroll
    for (int i = 0; i < 2; ++i)
        #pragma unroll
        for (int j = 0; j < 2; ++j) {
            int col = colBase + wn + j * 16 + cq;
            #pragma unroll
            for (int r = 0; r < 4; ++r) {
                int row = rowBase + wm + i * 16 + rq + r;
                R[(size_t)row * 256 + col] = acc[i][j][r];
            }
        }
}

// ---------------- gateup: 128x128 tile, BK=32, dbuf 2-phase, 4 waves 2x2 of 64x64 -------
// H2 = silu(x Gt) * (x Ut), bf16. Grid 1024, XCD decode.
// MODE 0: all fp32 reg-staged. MODE 1: xb g2l16 + W fp32 reg-staged (round-4 winner shape).
// MODE 2: xb g2l16 + W *bf16* reg-staged (same mixed shape, half weight bytes, no cvt).
template<int MODE>
__global__ __launch_bounds__(256, 2) void gemm_gateup(
    const float* __restrict__ Xf, const u16* __restrict__ Xb,
    const float* __restrict__ GWf, const float* __restrict__ UWf,
    const u16* __restrict__ GWb, const u16* __restrict__ UWb,
    u16* __restrict__ H2) {
    __shared__ __align__(16) u16 As[2][4096];
    __shared__ __align__(16) u16 Gs[2][4096];
    __shared__ __align__(16) u16 Us[2][4096];
    int tid = threadIdx.x, lane = tid & 63, wave = tid >> 6;
    int b = blockIdx.x, xcd = b & 7, ii = b >> 3;
    int by = xcd * 4 + (ii >> 5), bx = ii & 31;
    int rowBase = by * 128, colBase = bx * 128;
    int wm = (wave >> 1) * 64, wn = (wave & 1) * 64;
    f32x4 accg[4][4] = {}, accu[4][4] = {};
    float4 av[4], gv[4], uv[4];
    uint4 gv2[2], uv2[2];
    if constexpr (MODE >= 1) stageA32(Xb + (size_t)rowBase * 1024, 1024, As[0], tid);
    else                     { loadT32(Xf + (size_t)rowBase * 1024, 1024, tid, av);
                               writeT32(av, As[0], tid); }
    if constexpr (MODE == 2) {
        loadB32bf(GWb + (size_t)colBase * 1024, 1024, tid, gv2);
        loadB32bf(UWb + (size_t)colBase * 1024, 1024, tid, uv2);
        writeB32bf(gv2, Gs[0], tid);
        writeB32bf(uv2, Us[0], tid);
    } else {
        loadT32(GWf + (size_t)colBase * 1024, 1024, tid, gv);
        loadT32(UWf + (size_t)colBase * 1024, 1024, tid, uv);
        writeT32(gv, Gs[0], tid);
        writeT32(uv, Us[0], tid);
    }
    __syncthreads();
    int cur = 0;
    for (int t = 0; t < 32; ++t) {
        if (t < 31) {  // issue next-tile loads BEFORE compute
            int k0 = (t + 1) * 32;
            if constexpr (MODE >= 1) stageA32(Xb + (size_t)rowBase * 1024 + k0, 1024, As[cur ^ 1], tid);
            else                     loadT32(Xf + (size_t)rowBase * 1024 + k0, 1024, tid, av);
            if constexpr (MODE == 2) {
                loadB32bf(GWb + (size_t)colBase * 1024 + k0, 1024, tid, gv2);
                loadB32bf(UWb + (size_t)colBase * 1024 + k0, 1024, tid, uv2);
            } else {
                loadT32(GWf + (size_t)colBase * 1024 + k0, 1024, tid, gv);
                loadT32(UWf + (size_t)colBase * 1024 + k0, 1024, tid, uv);
            }
        }
        bf16x8 gf[4], uf[4];
        #pragma unroll
        for (int j = 0; j < 4; ++j) { gf[j] = frag32s(Gs[cur], wn + j * 16, lane);
                                      uf[j] = frag32s(Us[cur], wn + j * 16, lane); }
        #pragma unroll
        for (int i = 0; i < 4; ++i) {
            bf16x8 af = frag32s(As[cur], wm + i * 16, lane);
            #pragma unroll
            for (int j = 0; j < 4; ++j) {
                accg[i][j] = __builtin_amdgcn_mfma_f32_16x16x32_bf16(af, gf[j], accg[i][j], 0, 0, 0);
                accu[i][j] = __builtin_amdgcn_mfma_f32_16x16x32_bf16(af, uf[j], accu[i][j], 0, 0, 0);
            }
        }
        if (t < 31) {  // write next tile AFTER compute (loads drained here, not earlier)
            if constexpr (MODE == 0) writeT32(av, As[cur ^ 1], tid);
            if constexpr (MODE == 2) { writeB32bf(gv2, Gs[cur ^ 1], tid);
                                       writeB32bf(uv2, Us[cur ^ 1], tid); }
            else if constexpr (MODE < 2) { writeT32(gv, Gs[cur ^ 1], tid);
                                           writeT32(uv, Us[cur ^ 1], tid); }
        }
        __syncthreads();
        cur ^= 1;
    }
    int rq = (lane >> 4) * 4, cq = lane & 15;
    #pragma unroll
    for (int i = 0; i < 4; ++i)
        #pragma unroll
        for (int j = 0; j < 4; ++j) {
            int col = colBase + wn + j * 16 + cq;
            #pragma unroll
            for (int r = 0; r < 4; ++r) {
                int row = rowBase + wm + i * 16 + rq + r;
                float gvv = accg[i][j][r], uvv = accu[i][j][r];
                float h = (gvv / (1.f + __expf(-gvv))) * uvv;   // silu(g)*u
                H2[(size_t)row * 4096 + col] = f2bf(h);
            }
        }
}

// ---------------- down: Out += H2 @ dw^T. 64x64 tile, BK=64, 256 thr (4 waves 2x2 of
// 32x32), dbuf 2-phase, grid 1024 (4 blk/CU), XCD decode. A g2l16; B reg-staged (mixed). --
template<int DMODE>   // 0 = B fp32 reg-staged; 1 = B bf16 reg-staged
__global__ __launch_bounds__(256, 4) void gemm_down64(
    const u16* __restrict__ H2, const float* __restrict__ DWf, const u16* __restrict__ DWb,
    float* __restrict__ Out) {
    __shared__ __align__(16) u16 As[2][4096];
    __shared__ __align__(16) u16 Bs[2][4096];
    int tid = threadIdx.x, lane = tid & 63, wave = tid >> 6;
    int b = blockIdx.x, xcd = b & 7, ii = b >> 3;
    int by = xcd * 8 + (ii >> 4), bx = ii & 15;
    int rowBase = by * 64, colBase = bx * 64;
    const u16* Ap = H2 + (size_t)rowBase * 4096;
    int wm = (wave >> 1) * 32, wn = (wave & 1) * 32;
    f32x4 acc[2][2] = {};
    float4 bv[4];
    uint4 bv2[2];
    stageA64<256>(Ap, 4096, As[0], tid);
    if constexpr (DMODE == 1) { loadB64bf(DWb + (size_t)colBase * 4096, 4096, tid, bv2);
                                writeB64bf(bv2, Bs[0], tid); }
    else                      { loadT64_256(DWf + (size_t)colBase * 4096, 4096, tid, bv);
                                writeT64_256(bv, Bs[0], tid); }
    __syncthreads();
    int cur = 0;
    for (int t = 0; t < 64; ++t) {
        if (t < 63) {
            int k0 = (t + 1) * 64;
            stageA64<256>(Ap + k0, 4096, As[cur ^ 1], tid);
            if constexpr (DMODE == 1) loadB64bf(DWb + (size_t)colBase * 4096 + k0, 4096, tid, bv2);
            else                      loadT64_256(DWf + (size_t)colBase * 4096 + k0, 4096, tid, bv);
        }
        #pragma unroll
        for (int ks = 0; ks < 2; ++ks) {
            bf16x8 af[2], bfr[2];
            #pragma unroll
            for (int i = 0; i < 2; ++i) af[i] = frag64s(As[cur], wm + i * 16, ks, lane);
            #pragma unroll
            for (int j = 0; j < 2; ++j) bfr[j] = frag64s(Bs[cur], wn + j * 16, ks, lane);
            #pragma unroll
            for (int i = 0; i < 2; ++i)
                #pragma unroll
                for (int j = 0; j < 2; ++j)
                    acc[i][j] = __builtin_amdgcn_mfma_f32_16x16x32_bf16(af[i], bfr[j], acc[i][j], 0, 0, 0);
        }
        if (t < 63) {
            if constexpr (DMODE == 1) writeB64bf(bv2, Bs[cur ^ 1], tid);
            else                      writeT64_256(bv, Bs[cur ^ 1], tid);
        }
        __syncthreads();
        cur ^= 1;
    }
    int rq = (lane >> 4) * 4, cq = lane & 15;
    #pragma unroll
    for (int i = 0; i < 2; ++i)
        #pragma unroll
        for (int j = 0; j < 2; ++j) {
            int col = colBase + wn + j * 16 + cq;
            #pragma unroll
            for (int r = 0; r < 4; ++r) {
                int row = rowBase + wm + i * 16 + rq + r;
                size_t o = (size_t)row * 1024 + col;
                Out[o] = acc[i][j][r] + Out[o];   // add experts term (same-thread RMW)
            }
        }
}

// ---------------- expert combine (round-1 exact: 4.6KB LDS, high occupancy) -------------
__global__ __launch_bounds__(256) void expert_store(
    const float* __restrict__ X, const float* __restrict__ UE, const float* __restrict__ DE,
    const int* __restrict__ idxs, const float* __restrict__ wts, float* __restrict__ Out) {
    int n = blockIdx.x, tid = threadIdx.x;
    int lane = tid & 63, wave = tid >> 6;
    __shared__ float xs[1024];
    __shared__ float ews[16];
    __shared__ int sidx[16];
    __shared__ float swt[16];
    if (tid < 16) {
        sidx[tid] = min(max(idxs[n * 16 + tid], 0), 16383);  // clamp: no wild gathers
        swt[tid] = wts[n * 16 + tid];
    }
    {
        float4 v = reinterpret_cast<const float4*>(X + (size_t)n * 1024)[tid];
        *reinterpret_cast<float4*>(xs + tid * 4) = v;
    }
    __syncthreads();
    #pragma unroll
    for (int q = 0; q < 4; ++q) {
        int e = wave * 4 + q;
        const float* row = UE + (size_t)sidx[e] * 1024;
        float acc = 0.f;
        #pragma unroll
        for (int c = 0; c < 4; ++c) {
            int h = c * 256 + lane * 4;
            float4 a = *reinterpret_cast<const float4*>(row + h);
            float4 xv = *reinterpret_cast<const float4*>(xs + h);
            acc += a.x * xv.x + a.y * xv.y + a.z * xv.z + a.w * xv.w;
        }
        acc = wave_sum(acc);
        if (lane == 0) {
            float s = acc / (1.f + __expf(-acc));   // silu
            ews[e] = s * swt[e];
        }
    }
    __syncthreads();
    float4 a = make_float4(0.f, 0.f, 0.f, 0.f);
    int h = tid * 4;
    #pragma unroll
    for (int e = 0; e < 16; ++e) {
        const float* row = DE + (size_t)sidx[e] * 1024;
        float4 v = *reinterpret_cast<const float4*>(row + h);
        float w = ews[e];
        a.x += w * v.x; a.y += w * v.y;
        a.z += w * v.z; a.w += w * v.w;
    }
    reinterpret_cast<float4*>(Out + (size_t)n * 1024)[tid] = a;
}

// ---------------- router stats / topk (proven) ----------------
__global__ void bn_stats(const float* __restrict__ R, float* __restrict__ stats) {
    int c = threadIdx.x;
    int r0 = blockIdx.x * 64;
    float s = 0.f, s2 = 0.f;
    for (int r = r0; r < r0 + 64; ++r) {
        float v = R[(size_t)r * 256 + c];
        s += v; s2 += v * v;
    }
    atomicAdd(&stats[c], s);
    atomicAdd(&stats[256 + c], s2);
}

__global__ __launch_bounds__(64) void router_topk(
    const float* __restrict__ R, const float* __restrict__ stats,
    int* __restrict__ idx_out, float* __restrict__ wt_out) {
    int n = blockIdx.x, lane = threadIdx.x;
    const float invN = 1.0f / 4096.0f;
    float z[4];
    #pragma unroll
    for (int p = 0; p < 4; ++p) {
        int c = p * 64 + lane;
        float mean = stats[c] * invN;
        float var = fmaxf(stats[256 + c] * invN - mean * mean, 0.f);  // biased var
        float v = R[(size_t)n * 256 + c];
        z[p] = (v - mean) * rsqrtf(var + 1e-5f);
    }
    float mx = wave_max(fmaxf(z[0], z[1]));
    float sx = __logf(wave_sum(__expf(z[0] - mx) + __expf(z[1] - mx)));
    float lx0 = z[0] - mx - sx, lx1 = z[1] - mx - sx;
    float my = wave_max(fmaxf(z[2], z[3]));
    float sy = __logf(wave_sum(__expf(z[2] - my) + __expf(z[3] - my)));
    float ly0 = z[2] - my - sy, ly1 = z[3] - my - sy;

    __shared__ float tx[16], ty[16];
    __shared__ int txc[16], tyc[16];
    float v0 = lx0, v1 = lx1;
    for (int t = 0; t < 16; ++t) {
        float bv; int bc;
        if (v1 > v0) { bv = v1; bc = lane + 64; } else { bv = v0; bc = lane; }
        wave_argmax(bv, bc);
        if (lane == 0) { tx[t] = bv; txc[t] = bc; }
        if (bc == lane) v0 = NEG_INF;
        else if (bc == lane + 64) v1 = NEG_INF;
    }
    v0 = ly0; v1 = ly1;
    for (int t = 0; t < 16; ++t) {
        float bv; int bc;
        if (v1 > v0) { bv = v1; bc = lane + 64; } else { bv = v0; bc = lane; }
        wave_argmax(bv, bc);
        if (lane == 0) { ty[t] = bv; tyc[t] = bc; }
        if (bc == lane) v0 = NEG_INF;
        else if (bc == lane + 64) v1 = NEG_INF;
    }
    __syncthreads();
    float cv[4]; int ci[4];
    #pragma unroll
    for (int p = 0; p < 4; ++p) {
        int pid = p * 64 + lane;
        cv[p] = tx[pid >> 4] + ty[pid & 15];
        ci[p] = pid;
    }
    for (int t = 0; t < 16; ++t) {
        float bv = cv[0]; int bc = ci[0];
        #pragma unroll
        for (int p = 1; p < 4; ++p)
            if (cv[p] > bv) { bv = cv[p]; bc = ci[p]; }
        wave_argmax(bv, bc);
        if (lane == 0) {
            idx_out[n * 16 + t] = txc[bc >> 4] * 128 + tyc[bc & 15];
            wt_out[n * 16 + t] = __expf(bv);
        }
        #pragma unroll
        for (int p = 0; p < 4; ++p)
            if (ci[p] == bc) cv[p] = NEG_INF;
    }
}

// ---------------- host ----------------
// Workspace tiers:
//   base 34.1MB: stats 16K | idx 256K | wt 256K | union32 { R 4MB -> H2 32MB }
//   tier1 (+xb 8MB, >=42,483,712): x pre-converted -> router/gateup A via g2l16
//   tier2 (+gwb,uwb,dwb 24MB, >=67,649,536): weights bf16 -> reg-staged bf16 B-tiles
//     (mixed staging: ONE g2l16 operand + reg-staged rest; round-5 showed all-g2l16
//      serializes on the LDS-DMA path: 144 -> 187us).
// All conversions are the same RNE cast previously applied in-flight: bit-identical output.
extern "C" void kernel_launch(void* const* d_in, const int* in_sizes, int n_in,
                              void* d_out, int out_size, void* d_ws, size_t ws_size,
                              hipStream_t stream) {
    const float* x   = (const float*)d_in[0];   // [4096,1024]
    const float* gw  = (const float*)d_in[1];   // [4096,1024]
    const float* uw  = (const float*)d_in[2];   // [4096,1024]
    const float* dw  = (const float*)d_in[3];   // [1024,4096]
    const float* rxw = (const float*)d_in[4];   // [128,1024]
    const float* ryw = (const float*)d_in[5];   // [128,1024]
    const float* ue  = (const float*)d_in[6];   // [16384,1024]
    const float* de  = (const float*)d_in[7];   // [16384,1024]
    float* out = (float*)d_out;                 // [4096,1024] fp32

    char* p = (char*)d_ws;
    float* stats = (float*)p; p += 16384;
    int*   idxb  = (int*)p;   p += 262144;
    float* wtb   = (float*)p; p += 262144;
    float* R     = (float*)p;                   // [4096,256] fp32, dead after router_topk
    u16*   H2    = (u16*)p;                     // aliases R: [4096,4096] bf16 (dense phase)

    u16* xb  = (u16*)((char*)d_ws + 34095104ull);
    u16* gwb = (u16*)((char*)d_ws + 42483712ull);
    u16* uwb = (u16*)((char*)d_ws + 50872320ull);
    u16* dwb = (u16*)((char*)d_ws + 59260928ull);
    int tier = ws_size >= 67649536ull ? 2 : ws_size >= 42483712ull ? 1 : 0;

    hipMemsetAsync(stats, 0, 512 * sizeof(float), stream);
    if (tier == 2)      conv_all<<<4096, 256, 0, stream>>>(x, gw, uw, dw, xb, gwb, uwb, dwb);
    else if (tier == 1) conv_x<<<4096, 256, 0, stream>>>(x, xb);

    if (tier >= 1) gemm_router<true ><<<dim3(4, 64), 256, 0, stream>>>(x, xb, rxw, ryw, R);
    else           gemm_router<false><<<dim3(4, 64), 256, 0, stream>>>(x, (const u16*)x, rxw, ryw, R);
    bn_stats<<<64, 256, 0, stream>>>(R, stats);
    router_topk<<<4096, 64, 0, stream>>>(R, stats, idxb, wtb);
    expert_store<<<4096, 256, 0, stream>>>(x, ue, de, idxb, wtb, out);   // experts -> out

    if (tier == 2)      gemm_gateup<2><<<1024, 256, 0, stream>>>(x, xb, gw, uw, gwb, uwb, H2);
    else if (tier == 1) gemm_gateup<1><<<1024, 256, 0, stream>>>(x, xb, gw, uw, nullptr, nullptr, H2);
    else                gemm_gateup<0><<<1024, 256, 0, stream>>>(x, (const u16*)x, gw, uw, nullptr, nullptr, H2);

    if (tier == 2) gemm_down64<1><<<1024, 256, 0, stream>>>(H2, dw, dwb, out);
    else           gemm_down64<0><<<1024, 256, 0, stream>>>(H2, dw, (const u16*)dw, out);
}